// Round 13
// baseline (878.376 us; speedup 1.0000x reference)
//
#include <hip/hip_runtime.h>
#include <hip/hip_cooperative_groups.h>
#include <math.h>

namespace cg = cooperative_groups;

#define D_FEAT 128
#define NB_HIST 128
#define N_NODES_MAX 10016   // LDS histogram capacity (problem has 10000)

// bf16 helpers -------------------------------------------------------------
__device__ __forceinline__ unsigned short f2bf(float x) {   // round-nearest-even
    unsigned int b = __float_as_uint(x);
    return (unsigned short)((b + 0x7fffu + ((b >> 16) & 1u)) >> 16);
}
__device__ __forceinline__ float2 bf2_to_f2(unsigned int u) {
    return make_float2(__uint_as_float(u << 16), __uint_as_float(u & 0xffff0000u));
}

// ---------------------------------------------------------------------------
// ONE cooperative kernel, 4 phases separated by grid.sync():
//  P1: blocks [0,NB_HIST): LDS dst-histogram (lrank + per-block counts);
//      blocks [NB_HIST,G): raw-bf16 row conversion + invn (grid-stride).
//  P2: scanA per node (one wave/node, grid-stride): 128-lane intra-node
//      exclusive scan of hist column + ATOMIC region base (replaces scanB —
//      node regions need not be node-ordered, only contiguous; per-node
//      FP sum order is unchanged -> deterministic output).
//  P3: scatter: pos = beg[d] + hist[b][d] + lrank[e]; 2B src id store.
//  P4: single-pass fused dot+exp+aggregate (round-12 agg, grid-stride).
// All phases grid-stride with NO early returns (grid.sync safety).
// ---------------------------------------------------------------------------
__global__ __launch_bounds__(256) void mega_kernel(
        const float* __restrict__ feat,
        const int* __restrict__ src,
        const int* __restrict__ dst,
        const float* __restrict__ beta,
        unsigned int* __restrict__ nfb,
        float* __restrict__ invn,
        int* __restrict__ hist,
        unsigned short* __restrict__ lrank,
        unsigned short* __restrict__ src_sorted,
        int* __restrict__ beg,
        int* __restrict__ deg,
        int* __restrict__ gctr,
        float* __restrict__ out,
        int n_nodes, int n_edges, int epb) {
    cg::grid_group grid = cg::this_grid();
    __shared__ int lhist[N_NODES_MAX];
    const int G   = (int)gridDim.x;
    const int tid = (int)threadIdx.x;
    const int bid = (int)blockIdx.x;
    const int lane = tid & 63;
    const int wib  = tid >> 6;          // wave in block (0..3)

    // ---------------- Phase 1 ----------------
    if (bid < NB_HIST) {
        for (int i = tid; i < n_nodes; i += 256) lhist[i] = 0;
        __syncthreads();
        int e0 = bid * epb;
        int e1 = e0 + epb; if (e1 > n_edges) e1 = n_edges;
        for (int e = e0 + tid; e < e1; e += 256)
            lrank[e] = (unsigned short)atomicAdd(&lhist[dst[e]], 1);  // LDS atomic
        __syncthreads();
        for (int i = tid; i < n_nodes; i += 256)
            hist[bid * n_nodes + i] = lhist[i];
        if (bid == 0 && tid == 0) *gctr = 0;     // base counter for P2
    } else {
        // raw bf16 rows + invn; one wave per node, grid-stride over node blocks
        for (int nb4 = bid - NB_HIST; nb4 * 4 < n_nodes; nb4 += (G - NB_HIST)) {
            int node = nb4 * 4 + wib;
            if (node < n_nodes) {
                float2 f = ((const float2*)feat)[node * 64 + lane];
                float ss = f.x * f.x + f.y * f.y;
                #pragma unroll
                for (int off = 1; off < 64; off <<= 1)
                    ss += __shfl_xor(ss, off, 64);
                unsigned int lo = f2bf(f.x), hi = f2bf(f.y);
                nfb[node * 64 + lane] = (hi << 16) | lo;
                if (lane == 0) invn[node] = 1.0f / fmaxf(sqrtf(ss), 1e-12f);
            }
        }
    }
    __threadfence();
    grid.sync();

    // ---------------- Phase 2: scanA + atomic region base ----------------
    {
        int gw = bid * 4 + wib;
        int GW = G * 4;
        for (int node = gw; node < n_nodes; node += GW) {
            int idx0 = lane * n_nodes + node;
            int idx1 = (64 + lane) * n_nodes + node;
            int v0 = hist[idx0];
            int v1 = hist[idx1];
            int incl0 = v0;
            #pragma unroll
            for (int off = 1; off < 64; off <<= 1) {
                int t = __shfl_up(incl0, off, 64);
                if (lane >= off) incl0 += t;
            }
            int tot0 = __shfl(incl0, 63, 64);
            int incl1 = v1;
            #pragma unroll
            for (int off = 1; off < 64; off <<= 1) {
                int t = __shfl_up(incl1, off, 64);
                if (lane >= off) incl1 += t;
            }
            hist[idx0] = incl0 - v0;             // exclusive prefix, b = lane
            hist[idx1] = tot0 + incl1 - v1;      // exclusive prefix, b = 64+lane
            if (lane == 63) {
                int total = tot0 + incl1;        // node degree
                beg[node] = atomicAdd(gctr, total);
                deg[node] = total;
            }
        }
    }
    __threadfence();
    grid.sync();

    // ---------------- Phase 3: scatter ----------------
    for (int e = bid * 256 + tid; e < n_edges; e += G * 256) {
        int d = dst[e];
        int b = e / epb;
        int pos = beg[d] + hist[b * n_nodes + d] + (int)lrank[e];
        src_sorted[pos] = (unsigned short)src[e];
    }
    __threadfence();
    grid.sync();

    // ---------------- Phase 4: fused dot + exp + aggregate ----------------
    {
        int q  = lane >> 4;          // quarter id 0..3 -> edge j+q
        int ql = lane & 15;          // dims 8*ql .. 8*ql+7
        float bscale = beta[0];
        int gw = bid * 4 + wib;
        int GW = G * 4;
        for (int node = gw; node < n_nodes; node += GW) {
            int b0 = beg[node];
            int e0 = b0 + deg[node];
            float bd = bscale * invn[node];

            uint4 du = ((const uint4*)nfb)[(size_t)node * 16 + ql];
            float2 d0 = bf2_to_f2(du.x), d1 = bf2_to_f2(du.y);
            float2 d2 = bf2_to_f2(du.z), d3 = bf2_to_f2(du.w);

            float l = 0.0f;
            float a0 = 0.f, a1 = 0.f, a2 = 0.f, a3 = 0.f;
            float a4 = 0.f, a5 = 0.f, a6 = 0.f, a7 = 0.f;

            for (int base = b0; base < e0; base += 64) {
                int nb = e0 - base;
                if (nb > 64) nb = 64;
                int gi = base + lane;
                bool valid = gi < e0;
                int idx = valid ? (int)src_sorted[gi] : 0;
                float ivm = valid ? invn[idx] : 0.0f;   // 0 marks invalid edges

                #pragma unroll 4
                for (int j = 0; j < nb; j += 4) {
                    int jj = j + q;                     // quarter q -> edge j+q
                    int   sj  = __shfl(idx, jj, 64);    // 0 for invalid -> row 0
                    float inj = __shfl(ivm, jj, 64);    // 0 for invalid
                    uint4 u = ((const uint4*)nfb)[(size_t)sj * 16 + ql];
                    float2 f0 = bf2_to_f2(u.x), f1 = bf2_to_f2(u.y);
                    float2 f2 = bf2_to_f2(u.z), f3 = bf2_to_f2(u.w);
                    float part = f0.x * d0.x + f0.y * d0.y
                               + f1.x * d1.x + f1.y * d1.y
                               + f2.x * d2.x + f2.y * d2.y
                               + f3.x * d3.x + f3.y * d3.y;
                    part += __shfl_xor(part, 1, 64);    // intra-quarter reduce
                    part += __shfl_xor(part, 2, 64);
                    part += __shfl_xor(part, 4, 64);
                    part += __shfl_xor(part, 8, 64);    // all 16 lanes hold dot
                    float w = __expf(part * inj * bd);  // bounded: |beta*cos|<=beta
                    w = (inj > 0.0f) ? w : 0.0f;        // mask invalid edges
                    l += w;
                    a0 += w * f0.x;  a1 += w * f0.y;
                    a2 += w * f1.x;  a3 += w * f1.y;
                    a4 += w * f2.x;  a5 += w * f2.y;
                    a6 += w * f3.x;  a7 += w * f3.y;
                }
            }
            #pragma unroll
            for (int off = 1; off < 64; off <<= 1)
                l += __shfl_xor(l, off, 64);            // 16 * sum(w)
            a0 += __shfl_xor(a0, 16, 64); a0 += __shfl_xor(a0, 32, 64);
            a1 += __shfl_xor(a1, 16, 64); a1 += __shfl_xor(a1, 32, 64);
            a2 += __shfl_xor(a2, 16, 64); a2 += __shfl_xor(a2, 32, 64);
            a3 += __shfl_xor(a3, 16, 64); a3 += __shfl_xor(a3, 32, 64);
            a4 += __shfl_xor(a4, 16, 64); a4 += __shfl_xor(a4, 32, 64);
            a5 += __shfl_xor(a5, 16, 64); a5 += __shfl_xor(a5, 32, 64);
            a6 += __shfl_xor(a6, 16, 64); a6 += __shfl_xor(a6, 32, 64);
            a7 += __shfl_xor(a7, 16, 64); a7 += __shfl_xor(a7, 32, 64);
            float invl = (l > 0.0f) ? (16.0f / l) : 0.0f;
            if (q == 0) {
                float4* o = (float4*)out + (size_t)node * 32 + ql * 2;
                o[0] = make_float4(a0 * invl, a1 * invl, a2 * invl, a3 * invl);
                o[1] = make_float4(a4 * invl, a5 * invl, a6 * invl, a7 * invl);
            }
        }
    }
}

// ---------------------------------------------------------------------------
extern "C" void kernel_launch(void* const* d_in, const int* in_sizes, int n_in,
                              void* d_out, int out_size, void* d_ws, size_t ws_size,
                              hipStream_t stream) {
    const float* feat = (const float*)d_in[0];
    const int* src    = (const int*)d_in[1];
    const int* dst    = (const int*)d_in[2];
    const float* beta = (const float*)d_in[3];
    float* out = (float*)d_out;

    const int n_nodes = in_sizes[0] / D_FEAT;
    const int n_edges = in_sizes[1];
    const int epb = (n_edges + NB_HIST - 1) / NB_HIST;

    char* ws = (char*)d_ws;
    size_t off = 0;
    auto alloc = [&](size_t bytes) -> void* {
        void* p = ws + off;
        off += (bytes + 255) & ~(size_t)255;
        return p;
    };
    unsigned int*   nfb        = (unsigned int*)alloc((size_t)n_nodes * 64 * 4); // 2.56 MB
    float*          invn       = (float*)alloc((size_t)n_nodes * 4);
    int*            hist       = (int*)  alloc((size_t)NB_HIST * n_nodes * 4);   // 5.12 MB
    int*            begv       = (int*)  alloc((size_t)n_nodes * 4);
    int*            degv       = (int*)  alloc((size_t)n_nodes * 4);
    int*            gctr       = (int*)  alloc(256);
    unsigned short* lrank      = (unsigned short*)alloc((size_t)n_edges * 2);    // 1.28 MB
    unsigned short* src_sorted = (unsigned short*)alloc((size_t)n_edges * 2);    // 1.28 MB

    // co-residency-safe grid size (host-side; runs only at capture time)
    int blocks_per_cu = 0;
    hipOccupancyMaxActiveBlocksPerMultiprocessor(&blocks_per_cu, mega_kernel, 256, 0);
    if (blocks_per_cu < 1) blocks_per_cu = 1;
    int num_cu = 256;
    hipDeviceProp_t prop;
    if (hipGetDeviceProperties(&prop, 0) == hipSuccess && prop.multiProcessorCount > 0)
        num_cu = prop.multiProcessorCount;
    int G = blocks_per_cu * num_cu;
    if (G < NB_HIST + 1) G = NB_HIST + 1;   // need at least one normalize block

    void* args[] = {
        (void*)&feat, (void*)&src, (void*)&dst, (void*)&beta,
        (void*)&nfb, (void*)&invn, (void*)&hist, (void*)&lrank,
        (void*)&src_sorted, (void*)&begv, (void*)&degv, (void*)&gctr,
        (void*)&out, (void*)&n_nodes, (void*)&n_edges, (void*)&epb
    };
    hipLaunchCooperativeKernel((const void*)mega_kernel, dim3(G), dim3(256),
                               args, 0, stream);
}

// Round 15
// 228.267 us; speedup vs baseline: 3.8480x; 3.8480x over previous
//
#include <hip/hip_runtime.h>
#include <math.h>

#define D_FEAT 128
#define NB_HIST 128
#define N_NODES_MAX 10016   // LDS histogram capacity (problem has 10000)

// bf16 helpers -------------------------------------------------------------
__device__ __forceinline__ unsigned short f2bf(float x) {   // round-nearest-even
    unsigned int b = __float_as_uint(x);
    return (unsigned short)((b + 0x7fffu + ((b >> 16) & 1u)) >> 16);
}
__device__ __forceinline__ float2 bf2_to_f2(unsigned int u) {
    return make_float2(__uint_as_float(u << 16), __uint_as_float(u & 0xffff0000u));
}

// ---------------------------------------------------------------------------
// 1. Fused grid (ROUND-12 PROVEN):
//    blocks [0, NB_HIST): per-block LDS histogram of dst — no global atomics.
//      lrank[e] = rank of e within (block, dst); hist[b*n_nodes+n] = count.
//      Block 0 zeroes gctr (consumed by scanA next in stream order).
//    blocks [NB_HIST, ...): RAW bf16 rows + invn = 1/||f||. Rows stay
//      unnormalized: agg's accumulation needs raw feat[src] (round-14 bug:
//      normalized rows without de-normalization shrank output ~11x).
// ---------------------------------------------------------------------------
__global__ __launch_bounds__(256) void norm_hist_kernel(
        const float* __restrict__ feat,
        const int* __restrict__ dst,
        unsigned int* __restrict__ nfb,
        float* __restrict__ invn,
        int* __restrict__ hist,
        unsigned short* __restrict__ lrank,
        int* __restrict__ gctr,
        int n_nodes, int n_edges, int epb) {
    __shared__ int lhist[N_NODES_MAX];
    if ((int)blockIdx.x < NB_HIST) {
        int b = blockIdx.x;
        if (b == 0 && threadIdx.x == 0) *gctr = 0;   // base counter for scanA
        for (int i = threadIdx.x; i < n_nodes; i += 256) lhist[i] = 0;
        __syncthreads();
        int e0 = b * epb;
        int e1 = e0 + epb;
        if (e1 > n_edges) e1 = n_edges;
        for (int e = e0 + (int)threadIdx.x; e < e1; e += 256) {
            int d = dst[e];
            lrank[e] = (unsigned short)atomicAdd(&lhist[d], 1);  // LDS atomic
        }
        __syncthreads();
        for (int i = threadIdx.x; i < n_nodes; i += 256)
            hist[b * n_nodes + i] = lhist[i];
    } else {
        int node = ((int)(blockIdx.x - NB_HIST) * 256 + (int)threadIdx.x) >> 6;
        int lane = threadIdx.x & 63;
        if (node >= n_nodes) return;
        float2 f = ((const float2*)feat)[node * 64 + lane];
        float ss = f.x * f.x + f.y * f.y;
        #pragma unroll
        for (int off = 1; off < 64; off <<= 1)
            ss += __shfl_xor(ss, off, 64);
        unsigned int lo = f2bf(f.x), hi = f2bf(f.y);
        nfb[node * 64 + lane] = (hi << 16) | lo;
        if (lane == 0) invn[node] = 1.0f / fmaxf(sqrtf(ss), 1e-12f);
    }
}

// ---------------------------------------------------------------------------
// 2. scanA + atomic region base (replaces scanB kernel): one WAVE per node —
//    lane b holds hist[b][node] and hist[64+b][node]; two 64-lane scans with
//    carry -> exclusive intra-node base (in place). Lane 63 claims the node's
//    contiguous output region via ONE uncontended atomic. Region order is
//    nondeterministic but each node's content/order is deterministic.
// ---------------------------------------------------------------------------
__global__ __launch_bounds__(256) void scanA_kernel(int* __restrict__ hist,
                                                    int* __restrict__ beg,
                                                    int* __restrict__ deg,
                                                    int* __restrict__ gctr,
                                                    int n_nodes) {
    int node = (int)(blockIdx.x * blockDim.x + threadIdx.x) >> 6;
    int lane = threadIdx.x & 63;
    if (node >= n_nodes) return;
    int idx0 = lane * n_nodes + node;
    int idx1 = (64 + lane) * n_nodes + node;
    int v0 = hist[idx0];
    int v1 = hist[idx1];
    int incl0 = v0;
    #pragma unroll
    for (int off = 1; off < 64; off <<= 1) {
        int t = __shfl_up(incl0, off, 64);
        if (lane >= off) incl0 += t;
    }
    int tot0 = __shfl(incl0, 63, 64);
    int incl1 = v1;
    #pragma unroll
    for (int off = 1; off < 64; off <<= 1) {
        int t = __shfl_up(incl1, off, 64);
        if (lane >= off) incl1 += t;
    }
    hist[idx0] = incl0 - v0;                 // exclusive prefix, b = lane
    hist[idx1] = tot0 + incl1 - v1;          // exclusive prefix, b = 64+lane
    if (lane == 63) {
        int total = tot0 + incl1;            // node degree
        beg[node] = atomicAdd(gctr, total);
        deg[node] = total;
    }
}

// ---------------------------------------------------------------------------
// 3. Scatter (no atomics): pos = beg[d] + hist[b][d] + lrank[e]. 2B store.
// ---------------------------------------------------------------------------
__global__ void scatter_kernel(const int* __restrict__ src,
                               const int* __restrict__ dst,
                               const int* __restrict__ beg,
                               const int* __restrict__ hist,
                               const unsigned short* __restrict__ lrank,
                               unsigned short* __restrict__ src_sorted,
                               int n_nodes, int n_edges, int epb) {
    int e = blockIdx.x * blockDim.x + threadIdx.x;
    if (e >= n_edges) return;
    int d = dst[e];
    int b = e / epb;
    int pos = beg[d] + hist[b * n_nodes + d] + (int)lrank[e];
    src_sorted[pos] = (unsigned short)src[e];
}

// ---------------------------------------------------------------------------
// 4. SINGLE-PASS fused dot + exp + aggregation (ROUND-12 PROVEN, beg/deg
//    plumbing only). One wave per node. e = beta*cos bounded -> no max shift.
//    Quarter q handles edge j+q: gather RAW src row (uint4/lane, 16 lanes =
//    full row), dot vs register-held raw dst row, intra-quarter reduce,
//    w = __expf(dot * invn_s * (beta*invn_d)) — invn de-scales the dot;
//    accumulation uses the RAW row (matches reference p*feat[src]).
// ---------------------------------------------------------------------------
__global__ void agg_kernel(const unsigned int* __restrict__ nfb,
                           const float* __restrict__ invn,
                           const float* __restrict__ beta,
                           const int* __restrict__ beg,
                           const int* __restrict__ deg,
                           const unsigned short* __restrict__ src_sorted,
                           float* __restrict__ out, int n_nodes) {
    int node = (int)(blockIdx.x * blockDim.x + threadIdx.x) >> 6;
    int lane = threadIdx.x & 63;
    if (node >= n_nodes) return;
    int b0 = beg[node];
    int e0 = b0 + deg[node];
    int q  = lane >> 4;          // quarter id 0..3 -> edge j+q
    int ql = lane & 15;          // dims 8*ql .. 8*ql+7
    float bd = beta[0] * invn[node];   // fold beta and 1/||f_d||

    // dst row: each quarter holds the full 128-dim raw row (16 lanes x uint4)
    uint4 du = ((const uint4*)nfb)[(size_t)node * 16 + ql];
    float2 d0 = bf2_to_f2(du.x), d1 = bf2_to_f2(du.y);
    float2 d2 = bf2_to_f2(du.z), d3 = bf2_to_f2(du.w);

    float l = 0.0f;
    float a0 = 0.f, a1 = 0.f, a2 = 0.f, a3 = 0.f;
    float a4 = 0.f, a5 = 0.f, a6 = 0.f, a7 = 0.f;

    for (int base = b0; base < e0; base += 64) {
        int nb = e0 - base;
        if (nb > 64) nb = 64;
        int gi = base + lane;
        bool valid = gi < e0;
        int idx = valid ? (int)src_sorted[gi] : 0;
        float ivm = valid ? invn[idx] : 0.0f;   // 0 marks invalid edges

        #pragma unroll 4
        for (int j = 0; j < nb; j += 4) {
            int jj = j + q;                         // quarter q -> edge j+q
            int   sj  = __shfl(idx, jj, 64);        // 0 for invalid -> row 0
            float inj = __shfl(ivm, jj, 64);        // 0 for invalid
            uint4 u = ((const uint4*)nfb)[(size_t)sj * 16 + ql];
            float2 f0 = bf2_to_f2(u.x), f1 = bf2_to_f2(u.y);
            float2 f2 = bf2_to_f2(u.z), f3 = bf2_to_f2(u.w);
            float part = f0.x * d0.x + f0.y * d0.y + f1.x * d1.x + f1.y * d1.y
                       + f2.x * d2.x + f2.y * d2.y + f3.x * d3.x + f3.y * d3.y;
            part += __shfl_xor(part, 1, 64);        // intra-quarter reduce
            part += __shfl_xor(part, 2, 64);
            part += __shfl_xor(part, 4, 64);
            part += __shfl_xor(part, 8, 64);        // all 16 lanes hold dot
            float w = __expf(part * inj * bd);      // bounded: |beta*cos|<=beta
            w = (inj > 0.0f) ? w : 0.0f;            // mask invalid edges
            l += w;
            a0 += w * f0.x;  a1 += w * f0.y;        // RAW row accumulation
            a2 += w * f1.x;  a3 += w * f1.y;
            a4 += w * f2.x;  a5 += w * f2.y;
            a6 += w * f3.x;  a7 += w * f3.y;
        }
    }
    // each edge's w accumulated by all 16 lanes of its quarter -> 16*sum(w)
    #pragma unroll
    for (int off = 1; off < 64; off <<= 1)
        l += __shfl_xor(l, off, 64);
    // merge the four quarter-wave accumulator sets (same dims in all quarters)
    a0 += __shfl_xor(a0, 16, 64); a0 += __shfl_xor(a0, 32, 64);
    a1 += __shfl_xor(a1, 16, 64); a1 += __shfl_xor(a1, 32, 64);
    a2 += __shfl_xor(a2, 16, 64); a2 += __shfl_xor(a2, 32, 64);
    a3 += __shfl_xor(a3, 16, 64); a3 += __shfl_xor(a3, 32, 64);
    a4 += __shfl_xor(a4, 16, 64); a4 += __shfl_xor(a4, 32, 64);
    a5 += __shfl_xor(a5, 16, 64); a5 += __shfl_xor(a5, 32, 64);
    a6 += __shfl_xor(a6, 16, 64); a6 += __shfl_xor(a6, 32, 64);
    a7 += __shfl_xor(a7, 16, 64); a7 += __shfl_xor(a7, 32, 64);
    float invl = (l > 0.0f) ? (16.0f / l) : 0.0f;
    if (q == 0) {
        float4* o = (float4*)out + (size_t)node * 32 + ql * 2;
        o[0] = make_float4(a0 * invl, a1 * invl, a2 * invl, a3 * invl);
        o[1] = make_float4(a4 * invl, a5 * invl, a6 * invl, a7 * invl);
    }
}

// ---------------------------------------------------------------------------
extern "C" void kernel_launch(void* const* d_in, const int* in_sizes, int n_in,
                              void* d_out, int out_size, void* d_ws, size_t ws_size,
                              hipStream_t stream) {
    const float* feat = (const float*)d_in[0];
    const int* src    = (const int*)d_in[1];
    const int* dst    = (const int*)d_in[2];
    const float* beta = (const float*)d_in[3];
    float* out = (float*)d_out;

    const int n_nodes = in_sizes[0] / D_FEAT;
    const int n_edges = in_sizes[1];
    const int epb = (n_edges + NB_HIST - 1) / NB_HIST;

    char* ws = (char*)d_ws;
    size_t off = 0;
    auto alloc = [&](size_t bytes) -> void* {
        void* p = ws + off;
        off += (bytes + 255) & ~(size_t)255;
        return p;
    };
    unsigned int*   nfb        = (unsigned int*)alloc((size_t)n_nodes * 64 * 4); // 2.56 MB
    float*          invn       = (float*)alloc((size_t)n_nodes * 4);
    int*            hist       = (int*)  alloc((size_t)NB_HIST * n_nodes * 4);   // 5.12 MB
    int*            begv       = (int*)  alloc((size_t)n_nodes * 4);
    int*            degv       = (int*)  alloc((size_t)n_nodes * 4);
    int*            gctr       = (int*)  alloc(256);
    unsigned short* lrank      = (unsigned short*)alloc((size_t)n_edges * 2);    // 1.28 MB
    unsigned short* src_sorted = (unsigned short*)alloc((size_t)n_edges * 2);    // 1.28 MB

    int nb_norm = (n_nodes * 64 + 255) / 256;
    norm_hist_kernel<<<NB_HIST + nb_norm, 256, 0, stream>>>(
        feat, dst, nfb, invn, hist, lrank, gctr, n_nodes, n_edges, epb);

    scanA_kernel<<<(n_nodes + 3) / 4, 256, 0, stream>>>(
        hist, begv, degv, gctr, n_nodes);

    scatter_kernel<<<(n_edges + 255) / 256, 256, 0, stream>>>(
        src, dst, begv, hist, lrank, src_sorted, n_nodes, n_edges, epb);

    agg_kernel<<<(n_nodes + 3) / 4, 256, 0, stream>>>(
        nfb, invn, beta, begv, degv, src_sorted, out, n_nodes);
}

// Round 16
// 132.586 us; speedup vs baseline: 6.6250x; 1.7217x over previous
//
#include <hip/hip_runtime.h>
#include <math.h>

#define D_FEAT 128
#define NB_HIST 128
#define N_NODES_MAX 10016   // LDS histogram capacity (problem has 10000)

// bf16 helpers -------------------------------------------------------------
__device__ __forceinline__ unsigned short f2bf(float x) {   // round-nearest-even
    unsigned int b = __float_as_uint(x);
    return (unsigned short)((b + 0x7fffu + ((b >> 16) & 1u)) >> 16);
}
__device__ __forceinline__ float2 bf2_to_f2(unsigned int u) {
    return make_float2(__uint_as_float(u << 16), __uint_as_float(u & 0xffff0000u));
}

// ---------------------------------------------------------------------------
// 1. Fused grid:
//    blocks [0, NB_HIST): per-block LDS histogram of dst — NO global atomics.
//      lrank[e] = rank of e within (block, dst); hist[b*n_nodes+n] = count.
//    blocks [NB_HIST, ...): RAW bf16 rows + invn = 1/||f||.
//    (Raw rows: agg needs feat[src] for accumulation; dot is de-scaled by
//     invn_s*invn_d instead. Round-14 bug proved normalized-row accumulation
//     is wrong without de-normalization.)
// ---------------------------------------------------------------------------
__global__ __launch_bounds__(256) void norm_hist_kernel(
        const float* __restrict__ feat,
        const int* __restrict__ dst,
        unsigned int* __restrict__ nfb,
        float* __restrict__ invn,
        int* __restrict__ hist,
        unsigned short* __restrict__ lrank,
        int n_nodes, int n_edges, int epb) {
    __shared__ int lhist[N_NODES_MAX];
    if ((int)blockIdx.x < NB_HIST) {
        int b = blockIdx.x;
        for (int i = threadIdx.x; i < n_nodes; i += 256) lhist[i] = 0;
        __syncthreads();
        int e0 = b * epb;
        int e1 = e0 + epb;
        if (e1 > n_edges) e1 = n_edges;
        for (int e = e0 + (int)threadIdx.x; e < e1; e += 256) {
            int d = dst[e];
            lrank[e] = (unsigned short)atomicAdd(&lhist[d], 1);  // LDS atomic
        }
        __syncthreads();
        for (int i = threadIdx.x; i < n_nodes; i += 256)
            hist[b * n_nodes + i] = lhist[i];
    } else {
        int node = ((int)(blockIdx.x - NB_HIST) * 256 + (int)threadIdx.x) >> 6;
        int lane = threadIdx.x & 63;
        if (node >= n_nodes) return;
        float2 f = ((const float2*)feat)[node * 64 + lane];
        float ss = f.x * f.x + f.y * f.y;
        #pragma unroll
        for (int off = 1; off < 64; off <<= 1)
            ss += __shfl_xor(ss, off, 64);
        unsigned int lo = f2bf(f.x), hi = f2bf(f.y);
        nfb[node * 64 + lane] = (hi << 16) | lo;
        if (lane == 0) invn[node] = 1.0f / fmaxf(sqrtf(ss), 1e-12f);
    }
}

// ---------------------------------------------------------------------------
// 2a. scanA: one WAVE per node — lane b holds hist[b][node] and
//     hist[64+b][node]; two 64-lane scans with carry -> exclusive intra-node
//     base per hist block (in place), total -> cnt[node].
//     NO global atomics (round-15 lesson: 10000 same-address atomics = 120us).
// ---------------------------------------------------------------------------
__global__ __launch_bounds__(256) void scanA_kernel(int* __restrict__ hist,
                                                    int* __restrict__ cnt,
                                                    int n_nodes) {
    int node = (int)(blockIdx.x * blockDim.x + threadIdx.x) >> 6;
    int lane = threadIdx.x & 63;
    if (node >= n_nodes) return;
    int idx0 = lane * n_nodes + node;
    int idx1 = (64 + lane) * n_nodes + node;
    int v0 = hist[idx0];
    int v1 = hist[idx1];
    int incl0 = v0;
    #pragma unroll
    for (int off = 1; off < 64; off <<= 1) {
        int t = __shfl_up(incl0, off, 64);
        if (lane >= off) incl0 += t;
    }
    int tot0 = __shfl(incl0, 63, 64);
    int incl1 = v1;
    #pragma unroll
    for (int off = 1; off < 64; off <<= 1) {
        int t = __shfl_up(incl1, off, 64);
        if (lane >= off) incl1 += t;
    }
    hist[idx0] = incl0 - v0;                 // exclusive prefix, b = lane
    hist[idx1] = tot0 + incl1 - v1;          // exclusive prefix, b = 64+lane
    if (lane == 63) cnt[node] = tot0 + incl1;  // node degree
}

// ---------------------------------------------------------------------------
// 2b. scanB: exclusive scan of cnt -> offsets. One 1024-thread block (~4 us —
//     cheaper than any atomic-based launch-elimination scheme on this chip).
// ---------------------------------------------------------------------------
__global__ __launch_bounds__(1024) void scanB_kernel(const int* __restrict__ cnt,
                                                     int* __restrict__ offsets, int n) {
    __shared__ int wsum[16];
    __shared__ int total;
    int t = threadIdx.x;
    const int per = (n + 1023) >> 10;
    int beg = t * per;
    int end = beg + per;
    if (beg > n) beg = n;
    if (end > n) end = n;
    int local[16];
    int s = 0;
    for (int i = beg; i < end; ++i) { int v = cnt[i]; local[i - beg] = v; s += v; }
    int lane = t & 63, wid = t >> 6;
    int incl = s;
    #pragma unroll
    for (int off = 1; off < 64; off <<= 1) {
        int v = __shfl_up(incl, off, 64);
        if (lane >= off) incl += v;
    }
    if (lane == 63) wsum[wid] = incl;
    __syncthreads();
    if (t == 0) {
        int run = 0;
        #pragma unroll
        for (int w = 0; w < 16; ++w) { int v = wsum[w]; wsum[w] = run; run += v; }
        total = run;
    }
    __syncthreads();
    int base = wsum[wid] + (incl - s);
    for (int i = beg; i < end; ++i) { offsets[i] = base; base += local[i - beg]; }
    if (t == 0) offsets[n] = total;
}

// ---------------------------------------------------------------------------
// 3. Scatter (no atomics): pos = offsets[d] + hist[b][d] + lrank[e].
//    One 2B store: src id only.
// ---------------------------------------------------------------------------
__global__ void scatter_kernel(const int* __restrict__ src,
                               const int* __restrict__ dst,
                               const int* __restrict__ offsets,
                               const int* __restrict__ hist,
                               const unsigned short* __restrict__ lrank,
                               unsigned short* __restrict__ src_sorted,
                               int n_nodes, int n_edges, int epb) {
    int e = blockIdx.x * blockDim.x + threadIdx.x;
    if (e >= n_edges) return;
    int d = dst[e];
    int b = e / epb;
    int pos = offsets[d] + hist[b * n_nodes + d] + (int)lrank[e];
    src_sorted[pos] = (unsigned short)src[e];
}

// ---------------------------------------------------------------------------
// 4. SINGLE-PASS fused dot + exp + aggregation. One wave per node.
//    e = beta*cos is bounded (|cos|<=1) -> exp never overflows -> no
//    segment-max machinery. Quarter q handles edge j+q: gather RAW src row
//    (uint4/lane, 16 lanes = full 256B row), dot vs register-held raw dst
//    row, 4-step intra-quarter reduce (all 16 lanes get the dot),
//    w = __expf(dot * invn_s * (beta*invn_d)), accumulate w*row from the
//    SAME registers. One gather per edge.
// ---------------------------------------------------------------------------
__global__ void agg_kernel(const unsigned int* __restrict__ nfb,
                           const float* __restrict__ invn,
                           const float* __restrict__ beta,
                           const int* __restrict__ offsets,
                           const unsigned short* __restrict__ src_sorted,
                           float* __restrict__ out, int n_nodes) {
    int node = (int)(blockIdx.x * blockDim.x + threadIdx.x) >> 6;
    int lane = threadIdx.x & 63;
    if (node >= n_nodes) return;
    int beg = offsets[node];
    int end = offsets[node + 1];
    int q  = lane >> 4;          // quarter id 0..3 -> edge j+q
    int ql = lane & 15;          // dims 8*ql .. 8*ql+7
    float bd = beta[0] * invn[node];   // fold beta and 1/||f_d||

    // dst row: each quarter holds the full 128-dim raw row (16 lanes x uint4)
    uint4 du = ((const uint4*)nfb)[(size_t)node * 16 + ql];
    float2 d0 = bf2_to_f2(du.x), d1 = bf2_to_f2(du.y);
    float2 d2 = bf2_to_f2(du.z), d3 = bf2_to_f2(du.w);

    float l = 0.0f;
    float a0 = 0.f, a1 = 0.f, a2 = 0.f, a3 = 0.f;
    float a4 = 0.f, a5 = 0.f, a6 = 0.f, a7 = 0.f;

    for (int base = beg; base < end; base += 64) {
        int nb = end - base;
        if (nb > 64) nb = 64;
        int gi = base + lane;
        bool valid = gi < end;
        int idx = valid ? (int)src_sorted[gi] : 0;
        float ivm = valid ? invn[idx] : 0.0f;   // 0 marks invalid edges

        #pragma unroll 4
        for (int j = 0; j < nb; j += 4) {
            int jj = j + q;                         // quarter q -> edge j+q
            int   sj  = __shfl(idx, jj, 64);        // 0 for invalid -> row 0
            float inj = __shfl(ivm, jj, 64);        // 0 for invalid
            uint4 u = ((const uint4*)nfb)[(size_t)sj * 16 + ql];
            float2 f0 = bf2_to_f2(u.x), f1 = bf2_to_f2(u.y);
            float2 f2 = bf2_to_f2(u.z), f3 = bf2_to_f2(u.w);
            float part = f0.x * d0.x + f0.y * d0.y + f1.x * d1.x + f1.y * d1.y
                       + f2.x * d2.x + f2.y * d2.y + f3.x * d3.x + f3.y * d3.y;
            part += __shfl_xor(part, 1, 64);        // intra-quarter reduce
            part += __shfl_xor(part, 2, 64);
            part += __shfl_xor(part, 4, 64);
            part += __shfl_xor(part, 8, 64);        // all 16 lanes hold dot
            float w = __expf(part * inj * bd);      // bounded: |beta*cos|<=beta
            w = (inj > 0.0f) ? w : 0.0f;            // mask invalid edges
            l += w;
            a0 += w * f0.x;  a1 += w * f0.y;        // RAW row accumulation
            a2 += w * f1.x;  a3 += w * f1.y;
            a4 += w * f2.x;  a5 += w * f2.y;
            a6 += w * f3.x;  a7 += w * f3.y;
        }
    }
    // each edge's w accumulated by all 16 lanes of its quarter -> 16*sum(w)
    #pragma unroll
    for (int off = 1; off < 64; off <<= 1)
        l += __shfl_xor(l, off, 64);
    // merge the four quarter-wave accumulator sets (same dims in all quarters)
    a0 += __shfl_xor(a0, 16, 64); a0 += __shfl_xor(a0, 32, 64);
    a1 += __shfl_xor(a1, 16, 64); a1 += __shfl_xor(a1, 32, 64);
    a2 += __shfl_xor(a2, 16, 64); a2 += __shfl_xor(a2, 32, 64);
    a3 += __shfl_xor(a3, 16, 64); a3 += __shfl_xor(a3, 32, 64);
    a4 += __shfl_xor(a4, 16, 64); a4 += __shfl_xor(a4, 32, 64);
    a5 += __shfl_xor(a5, 16, 64); a5 += __shfl_xor(a5, 32, 64);
    a6 += __shfl_xor(a6, 16, 64); a6 += __shfl_xor(a6, 32, 64);
    a7 += __shfl_xor(a7, 16, 64); a7 += __shfl_xor(a7, 32, 64);
    float invl = (l > 0.0f) ? (16.0f / l) : 0.0f;
    if (q == 0) {
        float4* o = (float4*)out + (size_t)node * 32 + ql * 2;
        o[0] = make_float4(a0 * invl, a1 * invl, a2 * invl, a3 * invl);
        o[1] = make_float4(a4 * invl, a5 * invl, a6 * invl, a7 * invl);
    }
}

// ---------------------------------------------------------------------------
extern "C" void kernel_launch(void* const* d_in, const int* in_sizes, int n_in,
                              void* d_out, int out_size, void* d_ws, size_t ws_size,
                              hipStream_t stream) {
    const float* feat = (const float*)d_in[0];
    const int* src    = (const int*)d_in[1];
    const int* dst    = (const int*)d_in[2];
    const float* beta = (const float*)d_in[3];
    float* out = (float*)d_out;

    const int n_nodes = in_sizes[0] / D_FEAT;
    const int n_edges = in_sizes[1];
    const int epb = (n_edges + NB_HIST - 1) / NB_HIST;

    char* ws = (char*)d_ws;
    size_t off = 0;
    auto alloc = [&](size_t bytes) -> void* {
        void* p = ws + off;
        off += (bytes + 255) & ~(size_t)255;
        return p;
    };
    unsigned int*   nfb        = (unsigned int*)alloc((size_t)n_nodes * 64 * 4); // 2.56 MB
    float*          invn       = (float*)alloc((size_t)n_nodes * 4);
    int*            hist       = (int*)  alloc((size_t)NB_HIST * n_nodes * 4);   // 5.12 MB
    int*            cnt        = (int*)  alloc((size_t)n_nodes * 4);
    int*            offsets    = (int*)  alloc((size_t)(n_nodes + 1) * 4);
    unsigned short* lrank      = (unsigned short*)alloc((size_t)n_edges * 2);    // 1.28 MB
    unsigned short* src_sorted = (unsigned short*)alloc((size_t)n_edges * 2);    // 1.28 MB

    int nb_norm = (n_nodes * 64 + 255) / 256;
    norm_hist_kernel<<<NB_HIST + nb_norm, 256, 0, stream>>>(
        feat, dst, nfb, invn, hist, lrank, n_nodes, n_edges, epb);

    scanA_kernel<<<(n_nodes + 3) / 4, 256, 0, stream>>>(hist, cnt, n_nodes);

    scanB_kernel<<<1, 1024, 0, stream>>>(cnt, offsets, n_nodes);

    scatter_kernel<<<(n_edges + 255) / 256, 256, 0, stream>>>(
        src, dst, offsets, hist, lrank, src_sorted, n_nodes, n_edges, epb);

    agg_kernel<<<(n_nodes + 3) / 4, 256, 0, stream>>>(
        nfb, invn, beta, offsets, src_sorted, out, n_nodes);
}

// Round 17
// 127.212 us; speedup vs baseline: 6.9048x; 1.0422x over previous
//
#include <hip/hip_runtime.h>
#include <math.h>

#define D_FEAT 128
#define NB_HIST 128
#define N_NODES_MAX 10016   // LDS histogram capacity (problem has 10000)

// bf16 helpers -------------------------------------------------------------
__device__ __forceinline__ unsigned short f2bf(float x) {   // round-nearest-even
    unsigned int b = __float_as_uint(x);
    return (unsigned short)((b + 0x7fffu + ((b >> 16) & 1u)) >> 16);
}
__device__ __forceinline__ float2 bf2_to_f2(unsigned int u) {
    return make_float2(__uint_as_float(u << 16), __uint_as_float(u & 0xffff0000u));
}

// ---------------------------------------------------------------------------
// 1. Fused grid, 1024-THREAD BLOCKS (was 256): the hist blocks' critical
//    path is LDS housekeeping (zero 10016 + dump 10016), which at 256
//    threads was 78 of ~98 serial steps. At 1024 threads: 10+5+10 ~= 25.
//    blocks [0, NB_HIST): per-block LDS histogram of dst (LDS atomics only);
//      lrank[e] = rank of e within (block, dst); hist[b*n_nodes+n] = count.
//    blocks [NB_HIST, ...): RAW bf16 rows + invn = 1/||f||, 16 nodes/block.
// ---------------------------------------------------------------------------
__global__ __launch_bounds__(1024) void norm_hist_kernel(
        const float* __restrict__ feat,
        const int* __restrict__ dst,
        unsigned int* __restrict__ nfb,
        float* __restrict__ invn,
        int* __restrict__ hist,
        unsigned short* __restrict__ lrank,
        int n_nodes, int n_edges, int epb) {
    __shared__ int lhist[N_NODES_MAX];
    int tid = (int)threadIdx.x;
    if ((int)blockIdx.x < NB_HIST) {
        int b = blockIdx.x;
        for (int i = tid; i < n_nodes; i += 1024) lhist[i] = 0;
        __syncthreads();
        int e0 = b * epb;
        int e1 = e0 + epb;
        if (e1 > n_edges) e1 = n_edges;
        for (int e = e0 + tid; e < e1; e += 1024) {
            int d = dst[e];
            lrank[e] = (unsigned short)atomicAdd(&lhist[d], 1);  // LDS atomic
        }
        __syncthreads();
        for (int i = tid; i < n_nodes; i += 1024)
            hist[b * n_nodes + i] = lhist[i];
    } else {
        int node = ((int)blockIdx.x - NB_HIST) * 16 + (tid >> 6);
        int lane = tid & 63;
        if (node >= n_nodes) return;
        float2 f = ((const float2*)feat)[node * 64 + lane];
        float ss = f.x * f.x + f.y * f.y;
        #pragma unroll
        for (int off = 1; off < 64; off <<= 1)
            ss += __shfl_xor(ss, off, 64);
        unsigned int lo = f2bf(f.x), hi = f2bf(f.y);
        nfb[node * 64 + lane] = (hi << 16) | lo;
        if (lane == 0) invn[node] = 1.0f / fmaxf(sqrtf(ss), 1e-12f);
    }
}

// ---------------------------------------------------------------------------
// 2a. scanA: one WAVE per node — lane b holds hist[b][node] and
//     hist[64+b][node]; two 64-lane scans with carry -> exclusive intra-node
//     base per hist block (in place), total -> cnt[node].
//     NO global atomics (round-15 lesson: 10000 same-address atomics = 120us).
// ---------------------------------------------------------------------------
__global__ __launch_bounds__(256) void scanA_kernel(int* __restrict__ hist,
                                                    int* __restrict__ cnt,
                                                    int n_nodes) {
    int node = (int)(blockIdx.x * blockDim.x + threadIdx.x) >> 6;
    int lane = threadIdx.x & 63;
    if (node >= n_nodes) return;
    int idx0 = lane * n_nodes + node;
    int idx1 = (64 + lane) * n_nodes + node;
    int v0 = hist[idx0];
    int v1 = hist[idx1];
    int incl0 = v0;
    #pragma unroll
    for (int off = 1; off < 64; off <<= 1) {
        int t = __shfl_up(incl0, off, 64);
        if (lane >= off) incl0 += t;
    }
    int tot0 = __shfl(incl0, 63, 64);
    int incl1 = v1;
    #pragma unroll
    for (int off = 1; off < 64; off <<= 1) {
        int t = __shfl_up(incl1, off, 64);
        if (lane >= off) incl1 += t;
    }
    hist[idx0] = incl0 - v0;                 // exclusive prefix, b = lane
    hist[idx1] = tot0 + incl1 - v1;          // exclusive prefix, b = 64+lane
    if (lane == 63) cnt[node] = tot0 + incl1;  // node degree
}

// ---------------------------------------------------------------------------
// 2b. scanB: exclusive scan of cnt -> offsets. One 1024-thread block (~4 us —
//     cheaper than any atomic-based launch-elimination scheme on this chip).
// ---------------------------------------------------------------------------
__global__ __launch_bounds__(1024) void scanB_kernel(const int* __restrict__ cnt,
                                                     int* __restrict__ offsets, int n) {
    __shared__ int wsum[16];
    __shared__ int total;
    int t = threadIdx.x;
    const int per = (n + 1023) >> 10;
    int beg = t * per;
    int end = beg + per;
    if (beg > n) beg = n;
    if (end > n) end = n;
    int local[16];
    int s = 0;
    for (int i = beg; i < end; ++i) { int v = cnt[i]; local[i - beg] = v; s += v; }
    int lane = t & 63, wid = t >> 6;
    int incl = s;
    #pragma unroll
    for (int off = 1; off < 64; off <<= 1) {
        int v = __shfl_up(incl, off, 64);
        if (lane >= off) incl += v;
    }
    if (lane == 63) wsum[wid] = incl;
    __syncthreads();
    if (t == 0) {
        int run = 0;
        #pragma unroll
        for (int w = 0; w < 16; ++w) { int v = wsum[w]; wsum[w] = run; run += v; }
        total = run;
    }
    __syncthreads();
    int base = wsum[wid] + (incl - s);
    for (int i = beg; i < end; ++i) { offsets[i] = base; base += local[i - beg]; }
    if (t == 0) offsets[n] = total;
}

// ---------------------------------------------------------------------------
// 3. Scatter (no atomics): pos = offsets[d] + hist[b][d] + lrank[e].
//    One 2B store: src id only.
// ---------------------------------------------------------------------------
__global__ void scatter_kernel(const int* __restrict__ src,
                               const int* __restrict__ dst,
                               const int* __restrict__ offsets,
                               const int* __restrict__ hist,
                               const unsigned short* __restrict__ lrank,
                               unsigned short* __restrict__ src_sorted,
                               int n_nodes, int n_edges, int epb) {
    int e = blockIdx.x * blockDim.x + threadIdx.x;
    if (e >= n_edges) return;
    int d = dst[e];
    int b = e / epb;
    int pos = offsets[d] + hist[b * n_nodes + d] + (int)lrank[e];
    src_sorted[pos] = (unsigned short)src[e];
}

// ---------------------------------------------------------------------------
// 4. SINGLE-PASS fused dot + exp + aggregation. One wave per node.
//    e = beta*cos is bounded (|cos|<=1) -> exp never overflows -> no
//    segment-max machinery. Quarter q handles edge j+q: gather RAW src row
//    (uint4/lane, 16 lanes = full 256B row), dot vs register-held raw dst
//    row, 4-step intra-quarter reduce (all 16 lanes get the dot),
//    w = __expf(dot * invn_s * (beta*invn_d)), accumulate w*row from the
//    SAME registers. One gather per edge.
// ---------------------------------------------------------------------------
__global__ void agg_kernel(const unsigned int* __restrict__ nfb,
                           const float* __restrict__ invn,
                           const float* __restrict__ beta,
                           const int* __restrict__ offsets,
                           const unsigned short* __restrict__ src_sorted,
                           float* __restrict__ out, int n_nodes) {
    int node = (int)(blockIdx.x * blockDim.x + threadIdx.x) >> 6;
    int lane = threadIdx.x & 63;
    if (node >= n_nodes) return;
    int beg = offsets[node];
    int end = offsets[node + 1];
    int q  = lane >> 4;          // quarter id 0..3 -> edge j+q
    int ql = lane & 15;          // dims 8*ql .. 8*ql+7
    float bd = beta[0] * invn[node];   // fold beta and 1/||f_d||

    // dst row: each quarter holds the full 128-dim raw row (16 lanes x uint4)
    uint4 du = ((const uint4*)nfb)[(size_t)node * 16 + ql];
    float2 d0 = bf2_to_f2(du.x), d1 = bf2_to_f2(du.y);
    float2 d2 = bf2_to_f2(du.z), d3 = bf2_to_f2(du.w);

    float l = 0.0f;
    float a0 = 0.f, a1 = 0.f, a2 = 0.f, a3 = 0.f;
    float a4 = 0.f, a5 = 0.f, a6 = 0.f, a7 = 0.f;

    for (int base = beg; base < end; base += 64) {
        int nb = end - base;
        if (nb > 64) nb = 64;
        int gi = base + lane;
        bool valid = gi < end;
        int idx = valid ? (int)src_sorted[gi] : 0;
        float ivm = valid ? invn[idx] : 0.0f;   // 0 marks invalid edges

        #pragma unroll 4
        for (int j = 0; j < nb; j += 4) {
            int jj = j + q;                         // quarter q -> edge j+q
            int   sj  = __shfl(idx, jj, 64);        // 0 for invalid -> row 0
            float inj = __shfl(ivm, jj, 64);        // 0 for invalid
            uint4 u = ((const uint4*)nfb)[(size_t)sj * 16 + ql];
            float2 f0 = bf2_to_f2(u.x), f1 = bf2_to_f2(u.y);
            float2 f2 = bf2_to_f2(u.z), f3 = bf2_to_f2(u.w);
            float part = f0.x * d0.x + f0.y * d0.y + f1.x * d1.x + f1.y * d1.y
                       + f2.x * d2.x + f2.y * d2.y + f3.x * d3.x + f3.y * d3.y;
            part += __shfl_xor(part, 1, 64);        // intra-quarter reduce
            part += __shfl_xor(part, 2, 64);
            part += __shfl_xor(part, 4, 64);
            part += __shfl_xor(part, 8, 64);        // all 16 lanes hold dot
            float w = __expf(part * inj * bd);      // bounded: |beta*cos|<=beta
            w = (inj > 0.0f) ? w : 0.0f;            // mask invalid edges
            l += w;
            a0 += w * f0.x;  a1 += w * f0.y;        // RAW row accumulation
            a2 += w * f1.x;  a3 += w * f1.y;
            a4 += w * f2.x;  a5 += w * f2.y;
            a6 += w * f3.x;  a7 += w * f3.y;
        }
    }
    // each edge's w accumulated by all 16 lanes of its quarter -> 16*sum(w)
    #pragma unroll
    for (int off = 1; off < 64; off <<= 1)
        l += __shfl_xor(l, off, 64);
    // merge the four quarter-wave accumulator sets (same dims in all quarters)
    a0 += __shfl_xor(a0, 16, 64); a0 += __shfl_xor(a0, 32, 64);
    a1 += __shfl_xor(a1, 16, 64); a1 += __shfl_xor(a1, 32, 64);
    a2 += __shfl_xor(a2, 16, 64); a2 += __shfl_xor(a2, 32, 64);
    a3 += __shfl_xor(a3, 16, 64); a3 += __shfl_xor(a3, 32, 64);
    a4 += __shfl_xor(a4, 16, 64); a4 += __shfl_xor(a4, 32, 64);
    a5 += __shfl_xor(a5, 16, 64); a5 += __shfl_xor(a5, 32, 64);
    a6 += __shfl_xor(a6, 16, 64); a6 += __shfl_xor(a6, 32, 64);
    a7 += __shfl_xor(a7, 16, 64); a7 += __shfl_xor(a7, 32, 64);
    float invl = (l > 0.0f) ? (16.0f / l) : 0.0f;
    if (q == 0) {
        float4* o = (float4*)out + (size_t)node * 32 + ql * 2;
        o[0] = make_float4(a0 * invl, a1 * invl, a2 * invl, a3 * invl);
        o[1] = make_float4(a4 * invl, a5 * invl, a6 * invl, a7 * invl);
    }
}

// ---------------------------------------------------------------------------
extern "C" void kernel_launch(void* const* d_in, const int* in_sizes, int n_in,
                              void* d_out, int out_size, void* d_ws, size_t ws_size,
                              hipStream_t stream) {
    const float* feat = (const float*)d_in[0];
    const int* src    = (const int*)d_in[1];
    const int* dst    = (const int*)d_in[2];
    const float* beta = (const float*)d_in[3];
    float* out = (float*)d_out;

    const int n_nodes = in_sizes[0] / D_FEAT;
    const int n_edges = in_sizes[1];
    const int epb = (n_edges + NB_HIST - 1) / NB_HIST;

    char* ws = (char*)d_ws;
    size_t off = 0;
    auto alloc = [&](size_t bytes) -> void* {
        void* p = ws + off;
        off += (bytes + 255) & ~(size_t)255;
        return p;
    };
    unsigned int*   nfb        = (unsigned int*)alloc((size_t)n_nodes * 64 * 4); // 2.56 MB
    float*          invn       = (float*)alloc((size_t)n_nodes * 4);
    int*            hist       = (int*)  alloc((size_t)NB_HIST * n_nodes * 4);   // 5.12 MB
    int*            cnt        = (int*)  alloc((size_t)n_nodes * 4);
    int*            offsets    = (int*)  alloc((size_t)(n_nodes + 1) * 4);
    unsigned short* lrank      = (unsigned short*)alloc((size_t)n_edges * 2);    // 1.28 MB
    unsigned short* src_sorted = (unsigned short*)alloc((size_t)n_edges * 2);    // 1.28 MB

    int nb_norm = (n_nodes + 15) / 16;   // 16 nodes per 1024-thread block
    norm_hist_kernel<<<NB_HIST + nb_norm, 1024, 0, stream>>>(
        feat, dst, nfb, invn, hist, lrank, n_nodes, n_edges, epb);

    scanA_kernel<<<(n_nodes + 3) / 4, 256, 0, stream>>>(hist, cnt, n_nodes);

    scanB_kernel<<<1, 1024, 0, stream>>>(cnt, offsets, n_nodes);

    scatter_kernel<<<(n_edges + 255) / 256, 256, 0, stream>>>(
        src, dst, offsets, hist, lrank, src_sorted, n_nodes, n_edges, epb);

    agg_kernel<<<(n_nodes + 3) / 4, 256, 0, stream>>>(
        nfb, invn, beta, offsets, src_sorted, out, n_nodes);
}

// Round 18
// 122.203 us; speedup vs baseline: 7.1879x; 1.0410x over previous
//
#include <hip/hip_runtime.h>
#include <math.h>

#define D_FEAT 128
#define NB_HIST 128
#define N_NODES_MAX 10016   // LDS histogram capacity (problem has 10000)

// bf16 helpers -------------------------------------------------------------
__device__ __forceinline__ unsigned short f2bf(float x) {   // round-nearest-even
    unsigned int b = __float_as_uint(x);
    return (unsigned short)((b + 0x7fffu + ((b >> 16) & 1u)) >> 16);
}
__device__ __forceinline__ float2 bf2_to_f2(unsigned int u) {
    return make_float2(__uint_as_float(u << 16), __uint_as_float(u & 0xffff0000u));
}

// ---------------------------------------------------------------------------
// 1. Fused grid, 1024-thread blocks:
//    blocks [0, NB_HIST): per-block LDS histogram of dst (LDS atomics only);
//      lrank[e] = rank of e within (block, dst); hist[b*n_nodes+n] = count.
//    blocks [NB_HIST, ...): RAW bf16 rows + invn = 1/||f||, 16 nodes/block.
// ---------------------------------------------------------------------------
__global__ __launch_bounds__(1024) void norm_hist_kernel(
        const float* __restrict__ feat,
        const int* __restrict__ dst,
        unsigned int* __restrict__ nfb,
        float* __restrict__ invn,
        int* __restrict__ hist,
        unsigned short* __restrict__ lrank,
        int n_nodes, int n_edges, int epb) {
    __shared__ int lhist[N_NODES_MAX];
    int tid = (int)threadIdx.x;
    if ((int)blockIdx.x < NB_HIST) {
        int b = blockIdx.x;
        for (int i = tid; i < n_nodes; i += 1024) lhist[i] = 0;
        __syncthreads();
        int e0 = b * epb;
        int e1 = e0 + epb;
        if (e1 > n_edges) e1 = n_edges;
        for (int e = e0 + tid; e < e1; e += 1024) {
            int d = dst[e];
            lrank[e] = (unsigned short)atomicAdd(&lhist[d], 1);  // LDS atomic
        }
        __syncthreads();
        for (int i = tid; i < n_nodes; i += 1024)
            hist[b * n_nodes + i] = lhist[i];
    } else {
        int node = ((int)blockIdx.x - NB_HIST) * 16 + (tid >> 6);
        int lane = tid & 63;
        if (node >= n_nodes) return;
        float2 f = ((const float2*)feat)[node * 64 + lane];
        float ss = f.x * f.x + f.y * f.y;
        #pragma unroll
        for (int off = 1; off < 64; off <<= 1)
            ss += __shfl_xor(ss, off, 64);
        unsigned int lo = f2bf(f.x), hi = f2bf(f.y);
        nfb[node * 64 + lane] = (hi << 16) | lo;
        if (lane == 0) invn[node] = 1.0f / fmaxf(sqrtf(ss), 1e-12f);
    }
}

// ---------------------------------------------------------------------------
// 2a. scanA: one WAVE per node (16 nodes per 1024-thread block) — lane b
//     holds hist[b][node] and hist[64+b][node]; two 64-lane scans with carry
//     -> exclusive intra-node base (in place), total -> cnt[node].
//     NO global atomics (round-15: 10000 same-address atomics = 120us).
// ---------------------------------------------------------------------------
__global__ __launch_bounds__(1024) void scanA_kernel(int* __restrict__ hist,
                                                     int* __restrict__ cnt,
                                                     int n_nodes) {
    int node = (int)(blockIdx.x * blockDim.x + threadIdx.x) >> 6;
    int lane = threadIdx.x & 63;
    if (node >= n_nodes) return;
    int idx0 = lane * n_nodes + node;
    int idx1 = (64 + lane) * n_nodes + node;
    int v0 = hist[idx0];
    int v1 = hist[idx1];
    int incl0 = v0;
    #pragma unroll
    for (int off = 1; off < 64; off <<= 1) {
        int t = __shfl_up(incl0, off, 64);
        if (lane >= off) incl0 += t;
    }
    int tot0 = __shfl(incl0, 63, 64);
    int incl1 = v1;
    #pragma unroll
    for (int off = 1; off < 64; off <<= 1) {
        int t = __shfl_up(incl1, off, 64);
        if (lane >= off) incl1 += t;
    }
    hist[idx0] = incl0 - v0;                 // exclusive prefix, b = lane
    hist[idx1] = tot0 + incl1 - v1;          // exclusive prefix, b = 64+lane
    if (lane == 63) cnt[node] = tot0 + incl1;  // node degree
}

// ---------------------------------------------------------------------------
// 2b. scanB: exclusive scan of cnt -> offsets. One 1024-thread block (~4 us —
//     cheaper than any atomic-based launch-elimination scheme on this chip).
// ---------------------------------------------------------------------------
__global__ __launch_bounds__(1024) void scanB_kernel(const int* __restrict__ cnt,
                                                     int* __restrict__ offsets, int n) {
    __shared__ int wsum[16];
    __shared__ int total;
    int t = threadIdx.x;
    const int per = (n + 1023) >> 10;
    int beg = t * per;
    int end = beg + per;
    if (beg > n) beg = n;
    if (end > n) end = n;
    int local[16];
    int s = 0;
    for (int i = beg; i < end; ++i) { int v = cnt[i]; local[i - beg] = v; s += v; }
    int lane = t & 63, wid = t >> 6;
    int incl = s;
    #pragma unroll
    for (int off = 1; off < 64; off <<= 1) {
        int v = __shfl_up(incl, off, 64);
        if (lane >= off) incl += v;
    }
    if (lane == 63) wsum[wid] = incl;
    __syncthreads();
    if (t == 0) {
        int run = 0;
        #pragma unroll
        for (int w = 0; w < 16; ++w) { int v = wsum[w]; wsum[w] = run; run += v; }
        total = run;
    }
    __syncthreads();
    int base = wsum[wid] + (incl - s);
    for (int i = beg; i < end; ++i) { offsets[i] = base; base += local[i - beg]; }
    if (t == 0) offsets[n] = total;
}

// ---------------------------------------------------------------------------
// 3. Scatter (no atomics, 1024-thread blocks): pos = offsets[d] + hist[b][d]
//    + lrank[e]. One 2B store: src id only.
// ---------------------------------------------------------------------------
__global__ __launch_bounds__(1024) void scatter_kernel(
        const int* __restrict__ src,
        const int* __restrict__ dst,
        const int* __restrict__ offsets,
        const int* __restrict__ hist,
        const unsigned short* __restrict__ lrank,
        unsigned short* __restrict__ src_sorted,
        int n_nodes, int n_edges, int epb) {
    int e = blockIdx.x * blockDim.x + threadIdx.x;
    if (e >= n_edges) return;
    int d = dst[e];
    int b = e / epb;
    int pos = offsets[d] + hist[b * n_nodes + d] + (int)lrank[e];
    src_sorted[pos] = (unsigned short)src[e];
}

// ---------------------------------------------------------------------------
// 4. SINGLE-PASS fused dot + exp + aggregation. One wave per node.
//    e = beta*cos bounded -> no segment-max machinery. Quarter q handles
//    edge j+q: gather RAW src row (uint4/lane, 16 lanes = full 256B row),
//    dot vs register-held raw dst row, 4-step intra-quarter reduce,
//    w = __expf(dot * invn_s * (beta*invn_d)), accumulate w*row from the
//    SAME registers. unroll 8: 8 gathers in flight/lane vs L2 latency.
// ---------------------------------------------------------------------------
__global__ void agg_kernel(const unsigned int* __restrict__ nfb,
                           const float* __restrict__ invn,
                           const float* __restrict__ beta,
                           const int* __restrict__ offsets,
                           const unsigned short* __restrict__ src_sorted,
                           float* __restrict__ out, int n_nodes) {
    int node = (int)(blockIdx.x * blockDim.x + threadIdx.x) >> 6;
    int lane = threadIdx.x & 63;
    if (node >= n_nodes) return;
    int beg = offsets[node];
    int end = offsets[node + 1];
    int q  = lane >> 4;          // quarter id 0..3 -> edge j+q
    int ql = lane & 15;          // dims 8*ql .. 8*ql+7
    float bd = beta[0] * invn[node];   // fold beta and 1/||f_d||

    // dst row: each quarter holds the full 128-dim raw row (16 lanes x uint4)
    uint4 du = ((const uint4*)nfb)[(size_t)node * 16 + ql];
    float2 d0 = bf2_to_f2(du.x), d1 = bf2_to_f2(du.y);
    float2 d2 = bf2_to_f2(du.z), d3 = bf2_to_f2(du.w);

    float l = 0.0f;
    float a0 = 0.f, a1 = 0.f, a2 = 0.f, a3 = 0.f;
    float a4 = 0.f, a5 = 0.f, a6 = 0.f, a7 = 0.f;

    for (int base = beg; base < end; base += 64) {
        int nb = end - base;
        if (nb > 64) nb = 64;
        int gi = base + lane;
        bool valid = gi < end;
        int idx = valid ? (int)src_sorted[gi] : 0;
        float ivm = valid ? invn[idx] : 0.0f;   // 0 marks invalid edges

        #pragma unroll 8
        for (int j = 0; j < nb; j += 4) {
            int jj = j + q;                         // quarter q -> edge j+q
            int   sj  = __shfl(idx, jj, 64);        // 0 for invalid -> row 0
            float inj = __shfl(ivm, jj, 64);        // 0 for invalid
            uint4 u = ((const uint4*)nfb)[(size_t)sj * 16 + ql];
            float2 f0 = bf2_to_f2(u.x), f1 = bf2_to_f2(u.y);
            float2 f2 = bf2_to_f2(u.z), f3 = bf2_to_f2(u.w);
            float part = f0.x * d0.x + f0.y * d0.y + f1.x * d1.x + f1.y * d1.y
                       + f2.x * d2.x + f2.y * d2.y + f3.x * d3.x + f3.y * d3.y;
            part += __shfl_xor(part, 1, 64);        // intra-quarter reduce
            part += __shfl_xor(part, 2, 64);
            part += __shfl_xor(part, 4, 64);
            part += __shfl_xor(part, 8, 64);        // all 16 lanes hold dot
            float w = __expf(part * inj * bd);      // bounded: |beta*cos|<=beta
            w = (inj > 0.0f) ? w : 0.0f;            // mask invalid edges
            l += w;
            a0 += w * f0.x;  a1 += w * f0.y;        // RAW row accumulation
            a2 += w * f1.x;  a3 += w * f1.y;
            a4 += w * f2.x;  a5 += w * f2.y;
            a6 += w * f3.x;  a7 += w * f3.y;
        }
    }
    // each edge's w accumulated by all 16 lanes of its quarter -> 16*sum(w)
    #pragma unroll
    for (int off = 1; off < 64; off <<= 1)
        l += __shfl_xor(l, off, 64);
    // merge the four quarter-wave accumulator sets (same dims in all quarters)
    a0 += __shfl_xor(a0, 16, 64); a0 += __shfl_xor(a0, 32, 64);
    a1 += __shfl_xor(a1, 16, 64); a1 += __shfl_xor(a1, 32, 64);
    a2 += __shfl_xor(a2, 16, 64); a2 += __shfl_xor(a2, 32, 64);
    a3 += __shfl_xor(a3, 16, 64); a3 += __shfl_xor(a3, 32, 64);
    a4 += __shfl_xor(a4, 16, 64); a4 += __shfl_xor(a4, 32, 64);
    a5 += __shfl_xor(a5, 16, 64); a5 += __shfl_xor(a5, 32, 64);
    a6 += __shfl_xor(a6, 16, 64); a6 += __shfl_xor(a6, 32, 64);
    a7 += __shfl_xor(a7, 16, 64); a7 += __shfl_xor(a7, 32, 64);
    float invl = (l > 0.0f) ? (16.0f / l) : 0.0f;
    if (q == 0) {
        float4* o = (float4*)out + (size_t)node * 32 + ql * 2;
        o[0] = make_float4(a0 * invl, a1 * invl, a2 * invl, a3 * invl);
        o[1] = make_float4(a4 * invl, a5 * invl, a6 * invl, a7 * invl);
    }
}

// ---------------------------------------------------------------------------
extern "C" void kernel_launch(void* const* d_in, const int* in_sizes, int n_in,
                              void* d_out, int out_size, void* d_ws, size_t ws_size,
                              hipStream_t stream) {
    const float* feat = (const float*)d_in[0];
    const int* src    = (const int*)d_in[1];
    const int* dst    = (const int*)d_in[2];
    const float* beta = (const float*)d_in[3];
    float* out = (float*)d_out;

    const int n_nodes = in_sizes[0] / D_FEAT;
    const int n_edges = in_sizes[1];
    const int epb = (n_edges + NB_HIST - 1) / NB_HIST;

    char* ws = (char*)d_ws;
    size_t off = 0;
    auto alloc = [&](size_t bytes) -> void* {
        void* p = ws + off;
        off += (bytes + 255) & ~(size_t)255;
        return p;
    };
    unsigned int*   nfb        = (unsigned int*)alloc((size_t)n_nodes * 64 * 4); // 2.56 MB
    float*          invn       = (float*)alloc((size_t)n_nodes * 4);
    int*            hist       = (int*)  alloc((size_t)NB_HIST * n_nodes * 4);   // 5.12 MB
    int*            cnt        = (int*)  alloc((size_t)n_nodes * 4);
    int*            offsets    = (int*)  alloc((size_t)(n_nodes + 1) * 4);
    unsigned short* lrank      = (unsigned short*)alloc((size_t)n_edges * 2);    // 1.28 MB
    unsigned short* src_sorted = (unsigned short*)alloc((size_t)n_edges * 2);    // 1.28 MB

    int nb_norm = (n_nodes + 15) / 16;   // 16 nodes per 1024-thread block
    norm_hist_kernel<<<NB_HIST + nb_norm, 1024, 0, stream>>>(
        feat, dst, nfb, invn, hist, lrank, n_nodes, n_edges, epb);

    scanA_kernel<<<(n_nodes + 15) / 16, 1024, 0, stream>>>(hist, cnt, n_nodes);

    scanB_kernel<<<1, 1024, 0, stream>>>(cnt, offsets, n_nodes);

    scatter_kernel<<<(n_edges + 1023) / 1024, 1024, 0, stream>>>(
        src, dst, offsets, hist, lrank, src_sorted, n_nodes, n_edges, epb);

    agg_kernel<<<(n_nodes + 3) / 4, 256, 0, stream>>>(
        nfb, invn, beta, offsets, src_sorted, out, n_nodes);
}